// Round 17
// baseline (182.470 us; speedup 1.0000x reference)
//
#include <hip/hip_runtime.h>
#include <hip/hip_bf16.h>

#define R_RES 384
#define S_SEQ 128
#define CM 256
#define CC 32
#define CZ 128

typedef __attribute__((ext_vector_type(8))) short bf16x8;
typedef __attribute__((ext_vector_type(4))) float f32x4;
typedef __attribute__((ext_vector_type(4))) int i32x4;

__device__ __forceinline__ short tobf16(float f) {
    union { __hip_bfloat16 h; short s; } u;
    u.h = __float2bfloat16(f);
    return u.s;
}

__device__ __forceinline__ void lgkm_barrier() {
    asm volatile("s_waitcnt lgkmcnt(0)" ::: "memory");
    __builtin_amdgcn_s_barrier();
    __builtin_amdgcn_sched_barrier(0);
}

// ---------------- kernel 0a: w_out (1024,128) f32 -> wbTf 16x16x32-B-frag tiled bf16 ------
// frag(z16, k32) lane l: z = z16*16 + (l&15), k = k32*32 + (l>>4)*8 + j
__global__ void k_transpose_wout(const float* __restrict__ w_out, short* __restrict__ wbTf) {
    __shared__ float t[64][65];
    int k0 = blockIdx.x * 64;
    int z0 = blockIdx.y * 64;
    int tid = threadIdx.x;
    int c = tid & 63, rg = tid >> 6;
#pragma unroll
    for (int rr = 0; rr < 16; ++rr) {
        int kk = rg * 16 + rr;
        t[kk][c] = w_out[(size_t)(k0 + kk) * CZ + z0 + c];
    }
    __syncthreads();
#pragma unroll
    for (int l = 0; l < 2; ++l) {
        int id = l * 256 + tid;
        int f = id >> 6;
        int z16l = f >> 1, k32l = f & 1;
        int ln = id & 63;
        int zl = z16l * 16 + (ln & 15);
        int kl = k32l * 32 + (ln >> 4) * 8;
        bf16x8 pk;
#pragma unroll
        for (int j = 0; j < 8; ++j) pk[j] = tobf16(t[kl + j][zl]);
        int z16 = blockIdx.y * 4 + z16l;
        int k32 = blockIdx.x * 2 + k32l;
        *(bf16x8*)(wbTf + ((size_t)(z16 * 32 + k32) * 64 + ln) * 8) = pk;
    }
}

// ---------------- kernel 0b: pack w1|w2 (256,32) -> wcT (64,256) bf16 ----------------
__global__ void k_pack_w12(const float* __restrict__ w1, const float* __restrict__ w2,
                           short* __restrict__ wcT) {
    int idx = blockIdx.x * 256 + threadIdx.x;
    int k = idx >> 6, n = idx & 63;
    float v = (n < 32) ? w1[k * CC + n] : w2[k * CC + (n - 32)];
    wcT[n * CM + k] = tobf16(v);
}

// ---------------- kernel 1: LayerNorm + projections -> aTf, bTf fragment-tiled bf16 --------
__global__ __launch_bounds__(256) void k_ln_proj(
    const float* __restrict__ M, const float* __restrict__ ln_g, const float* __restrict__ ln_b,
    const float* __restrict__ b1, const float* __restrict__ b2,
    const short* __restrict__ wcT, short* __restrict__ aTf, short* __restrict__ bTf) {
    __shared__ short mnb[64 * 256];
    __shared__ short ab_s[2][32 * 72];
    int r = blockIdx.x >> 1;
    int s0 = (blockIdx.x & 1) * 64;
    int tid = threadIdx.x, lane = tid & 63, w = tid >> 6;
    int g = lane >> 4, r16 = lane & 15;
    float4 gv = *(const float4*)(ln_g + lane * 4);
    float4 bv = *(const float4*)(ln_b + lane * 4);
    for (int it = 0; it < 16; ++it) {
        int sl = it * 4 + w;
        float4 v = *(const float4*)(M + ((size_t)(s0 + sl) * R_RES + r) * CM + lane * 4);
        float sum = v.x + v.y + v.z + v.w;
        float sq = v.x * v.x + v.y * v.y + v.z * v.z + v.w * v.w;
#pragma unroll
        for (int off = 32; off; off >>= 1) {
            sum += __shfl_xor(sum, off);
            sq  += __shfl_xor(sq, off);
        }
        float mu = sum * (1.0f / 256.0f);
        float var = sq * (1.0f / 256.0f) - mu * mu;
        float rstd = rsqrtf(var + 1e-5f);
        short4 mnp;
        mnp.x = tobf16((v.x - mu) * rstd * gv.x + bv.x);
        mnp.y = tobf16((v.y - mu) * rstd * gv.y + bv.y);
        mnp.z = tobf16((v.z - mu) * rstd * gv.z + bv.z);
        mnp.w = tobf16((v.w - mu) * rstd * gv.w + bv.w);
        int byte = sl * 512 + lane * 8;
        byte ^= ((sl & 7) << 4);
        *(short4*)((char*)mnb + byte) = mnp;
    }
    __syncthreads();
    f32x4 acc[4] = {{0,0,0,0},{0,0,0,0},{0,0,0,0},{0,0,0,0}};
    int srow = w * 16 + r16;
#pragma unroll
    for (int ks = 0; ks < 8; ++ks) {
        int byte = srow * 512 + ks * 64 + g * 16;
        byte ^= ((srow & 7) << 4);
        bf16x8 af = *(const bf16x8*)((const char*)mnb + byte);
#pragma unroll
        for (int nt = 0; nt < 4; ++nt) {
            bf16x8 bf = *(const bf16x8*)(wcT + (nt * 16 + r16) * CM + ks * 32 + g * 8);
            acc[nt] = __builtin_amdgcn_mfma_f32_16x16x32_bf16(af, bf, acc[nt], 0, 0, 0);
        }
    }
#pragma unroll
    for (int nt = 0; nt < 4; ++nt) {
        int n = nt * 16 + r16;
        int x = n & 31, sel = n >> 5;
        float bias = sel ? b2[x] : b1[x];
#pragma unroll
        for (int rr = 0; rr < 4; ++rr) {
            int sl = w * 16 + g * 4 + rr;
            ab_s[sel][x * 72 + sl] = tobf16(acc[nt][rr] + bias);
        }
    }
    __syncthreads();
    int piece = tid >> 6;
    int fl = piece >> 1, kl = piece & 1;
    int ln = tid & 63;
    int x = fl * 16 + (ln & 15);
    int s_loc = kl * 32 + (ln >> 4) * 8;
    i32x4 va = *(const i32x4*)((const char*)ab_s[0] + (x * 72 + s_loc) * 2);
    i32x4 vb = *(const i32x4*)((const char*)ab_s[1] + (x * 72 + s_loc) * 2);
    size_t off = ((((size_t)r * 2 + fl) * 4 + (s0 >> 5) + kl) * 64 + ln) * 16;
    *(i32x4*)((char*)aTf + off) = va;
    *(i32x4*)((char*)bTf + off) = vb;
}

// ---------------- kernel 2: fused outer-product + w_out contraction (3 blk/CU) -------------
// grid (96 bj, 64 bi), 512 thr (8 waves), tile 192(i:6res) x 128(j:4res).
// LDS 48K: B [0,32K) staged -> A2 [0,48K) overlay (24p x 2K) -> Pp [24K,48K) overlay.
// __launch_bounds__(512,6) -> 85-VGPR cap -> 3 blocks/CU (144K LDS).
// ph2: 4m(48rows) x 2n(64cols) wave grid, acc[3][4]=48 regs, af fresh from L2.
// ph4: 16x16x32, (kh x zq), p handled as frag0(p=r16) + overlapping frag1(p=8+r16, store r16>=8).
__global__ __launch_bounds__(512, 6) void k_opm(
    const short* __restrict__ aTf, const short* __restrict__ bTf,
    const short* __restrict__ wbTf, const float* __restrict__ b_out,
    float* __restrict__ out) {
    __shared__ __align__(16) char smem[49152];
    int tid = threadIdx.x, lane = tid & 63, w = tid >> 6;
    int g = lane >> 4, r16 = lane & 15;
    int wm = w >> 1, wn = w & 1;     // ph2 roles: m-quarter (3 frags), n-half (4 frags)
    int kh = w & 1, zq = w >> 1;     // ph4 roles: k-half, z-quarter
    int bj = blockIdx.x, bi = blockIdx.y;

    // ---- stage B (32 KB) into smem[0,32K)
    const char* gB = (const char*)bTf + (size_t)bj * 32768;
#pragma unroll
    for (int q = 0; q < 4; ++q)
        __builtin_amdgcn_global_load_lds(
            (const __attribute__((address_space(1))) void*)(gB + q * 8192 + tid * 16),
            (__attribute__((address_space(3))) void*)(smem + q * 8192 + tid * 16), 16, 0, 0);
    const char* gA = (const char*)aTf + (size_t)bi * 49152;   // 6 res x 8KB
    asm volatile("s_waitcnt vmcnt(0)" ::: "memory");
    __syncthreads();

    // ---- ph2: O[192x128]; acc[mi][ni]: m = (wm*3+mi)*16+r16, n = wn*64+ni*16+g*4+rr
    f32x4 acc[3][4] = {};
#pragma unroll
    for (int ks = 0; ks < 4; ++ks) {
        bf16x8 af[3];
#pragma unroll
        for (int mi = 0; mi < 3; ++mi)
            af[mi] = *(const bf16x8*)(gA + ((wm * 3 + mi) * 4 + ks) * 1024 + lane * 16);
        // n-frags in two pairs to cap live registers
#pragma unroll
        for (int half = 0; half < 2; ++half) {
            bf16x8 bf0 = *(const bf16x8*)(smem + (((wn * 4 + half * 2 + 0) * 4 + ks) * 64 + lane) * 16);
            bf16x8 bf1 = *(const bf16x8*)(smem + (((wn * 4 + half * 2 + 1) * 4 + ks) * 64 + lane) * 16);
            __builtin_amdgcn_s_setprio(1);
#pragma unroll
            for (int mi = 0; mi < 3; ++mi) {
                acc[mi][half * 2 + 0] = __builtin_amdgcn_mfma_f32_16x16x32_bf16(bf0, af[mi], acc[mi][half * 2 + 0], 0, 0, 0);
                acc[mi][half * 2 + 1] = __builtin_amdgcn_mfma_f32_16x16x32_bf16(bf1, af[mi], acc[mi][half * 2 + 1], 0, 0, 0);
            }
            __builtin_amdgcn_s_setprio(0);
        }
    }
    lgkm_barrier();   // B reads done -> smem becomes A2 [0,48K)

    // ---- ph3: O -> A2 bf16 [p = i*4+j][k = x*32+y], dual-XOR swizzle. p in [0,24).
#pragma unroll
    for (int mi = 0; mi < 3; ++mi)
#pragma unroll
        for (int ni = 0; ni < 4; ++ni) {
            int fm = wm * 3 + mi;
            int i = fm >> 1, x = (fm & 1) * 16 + r16;
            int j = wn * 2 + (ni >> 1);
            int y0 = (ni & 1) * 16 + g * 4;
            int p = i * 4 + j;
            int byte = (p * 2048 + x * 64 + y0 * 2) ^ (((p & 7) ^ (x & 7)) << 4);
            short4 pk;
            pk.x = tobf16(acc[mi][ni][0]);
            pk.y = tobf16(acc[mi][ni][1]);
            pk.z = tobf16(acc[mi][ni][2]);
            pk.w = tobf16(acc[mi][ni][3]);
            *(short4*)(smem + byte) = pk;
        }

    // pre-issue wbf frags for ks2=0 (global; survive lgkm barrier)
    bf16x8 wcur0 = *(const bf16x8*)(wbTf + (((size_t)(zq * 2 + 0) * 32 + kh * 16 + 0) * 64 + lane) * 8);
    bf16x8 wcur1 = *(const bf16x8*)(wbTf + (((size_t)(zq * 2 + 1) * 32 + kh * 16 + 0) * 64 + lane) * 8);
    lgkm_barrier();   // A2 visible

    // ---- ph4: out[24p][128z] partials over k-half; wave (kh, zq); rolling wbf prefetch
    // c0/c1: p = r16 (frag0), z = zq*32 + {0,16} + g*4+rr; c2/c3: p = 8+r16 (frag1, store r16>=8)
    f32x4 c0 = {0,0,0,0}, c1 = {0,0,0,0}, c2 = {0,0,0,0}, c3 = {0,0,0,0};
#pragma unroll
    for (int ks2 = 0; ks2 < 16; ++ks2) {
        bf16x8 wn0, wn1;
        if (ks2 < 15) {
            wn0 = *(const bf16x8*)(wbTf + (((size_t)(zq * 2 + 0) * 32 + kh * 16 + ks2 + 1) * 64 + lane) * 8);
            wn1 = *(const bf16x8*)(wbTf + (((size_t)(zq * 2 + 1) * 32 + kh * 16 + ks2 + 1) * 64 + lane) * 8);
        }
        int x = kh * 16 + ks2;
        bf16x8 a2f0 = *(const bf16x8*)(smem + ((r16 * 2048 + x * 64 + g * 16)
                      ^ ((((r16 & 7) ^ (x & 7))) << 4)));
        bf16x8 a2f1 = *(const bf16x8*)(smem + (((8 + r16) * 2048 + x * 64 + g * 16)
                      ^ (((((8 + r16) & 7) ^ (x & 7))) << 4)));
        __builtin_amdgcn_s_setprio(1);
        c0 = __builtin_amdgcn_mfma_f32_16x16x32_bf16(wcur0, a2f0, c0, 0, 0, 0);
        c1 = __builtin_amdgcn_mfma_f32_16x16x32_bf16(wcur1, a2f0, c1, 0, 0, 0);
        c2 = __builtin_amdgcn_mfma_f32_16x16x32_bf16(wcur0, a2f1, c2, 0, 0, 0);
        c3 = __builtin_amdgcn_mfma_f32_16x16x32_bf16(wcur1, a2f1, c3, 0, 0, 0);
        __builtin_amdgcn_s_setprio(0);
        if (ks2 < 15) { wcur0 = wn0; wcur1 = wn1; }
    }
    lgkm_barrier();   // all A2 reads done -> [24K,48K) becomes Pp

    // ---- Pp write: [kh][24p][128z] f32 at [24K,48K), ^((p&7)<<4)
    {
        int zb0 = zq * 32 + g * 4;          // zt = 0
        int zb1 = zq * 32 + 16 + g * 4;     // zt = 1
        int p0 = r16;
        int b00 = (24576 + kh * 12288 + p0 * 512 + zb0 * 4) ^ ((p0 & 7) << 4);
        int b01 = (24576 + kh * 12288 + p0 * 512 + zb1 * 4) ^ ((p0 & 7) << 4);
        *(f32x4*)(smem + b00) = c0;
        *(f32x4*)(smem + b01) = c1;
        if (r16 >= 8) {
            int p1 = 8 + r16;               // 16..23
            int b10 = (24576 + kh * 12288 + p1 * 512 + zb0 * 4) ^ ((p1 & 7) << 4);
            int b11 = (24576 + kh * 12288 + p1 * 512 + zb1 * 4) ^ ((p1 & 7) << 4);
            *(f32x4*)(smem + b10) = c2;
            *(f32x4*)(smem + b11) = c3;
        }
    }
    lgkm_barrier();

    // ---- reduce kh-halves + coalesced f32x4 stores (384 active threads: 24p x 16 z-octs)
    if (tid < 384) {
        int p = tid >> 4;                   // 0..23
        int zo = (tid & 15) * 8;            // 0..120
        int sw = (p & 7) << 4;
        int base = 24576 + p * 512 + zo * 4;
        f32x4 u0 = *(const f32x4*)(smem + ((base) ^ sw));
        f32x4 u1 = *(const f32x4*)(smem + ((base + 16) ^ sw));
        f32x4 v0 = *(const f32x4*)(smem + ((base + 12288) ^ sw));
        f32x4 v1 = *(const f32x4*)(smem + ((base + 16 + 12288) ^ sw));
        float4 bo0 = *(const float4*)(b_out + zo);
        float4 bo1 = *(const float4*)(b_out + zo + 4);
        f32x4 r0, r1;
        r0[0] = (u0[0] + v0[0] + bo0.x) * (1.0f / 128.0f);
        r0[1] = (u0[1] + v0[1] + bo0.y) * (1.0f / 128.0f);
        r0[2] = (u0[2] + v0[2] + bo0.z) * (1.0f / 128.0f);
        r0[3] = (u0[3] + v0[3] + bo0.w) * (1.0f / 128.0f);
        r1[0] = (u1[0] + v1[0] + bo1.x) * (1.0f / 128.0f);
        r1[1] = (u1[1] + v1[1] + bo1.y) * (1.0f / 128.0f);
        r1[2] = (u1[2] + v1[2] + bo1.z) * (1.0f / 128.0f);
        r1[3] = (u1[3] + v1[3] + bo1.w) * (1.0f / 128.0f);
        int ig = bi * 6 + (p >> 2);
        int jg = bj * 4 + (p & 3);
        float* po = out + ((size_t)ig * R_RES + jg) * CZ + zo;
        *(f32x4*)(po) = r0;
        *(f32x4*)(po + 4) = r1;
    }
}

extern "C" void kernel_launch(void* const* d_in, const int* in_sizes, int n_in,
                              void* d_out, int out_size, void* d_ws, size_t ws_size,
                              hipStream_t stream) {
    const float* M     = (const float*)d_in[0];
    const float* ln_g  = (const float*)d_in[1];
    const float* ln_b  = (const float*)d_in[2];
    const float* w1    = (const float*)d_in[3];
    const float* b1    = (const float*)d_in[4];
    const float* w2    = (const float*)d_in[5];
    const float* b2    = (const float*)d_in[6];
    const float* w_out = (const float*)d_in[7];
    const float* b_out = (const float*)d_in[8];
    float* out = (float*)d_out;

    short* aTf  = (short*)d_ws;             // 384 res x 8 KB, fragment-tiled
    short* bTf  = aTf + 12288 * 128;
    short* wbTf = bTf + 12288 * 128;        // frag(z16, k32) tiled
    short* wcT  = wbTf + 128 * 1024;

    k_transpose_wout<<<dim3(16, 2), 256, 0, stream>>>(w_out, wbTf);
    k_pack_w12<<<64, 256, 0, stream>>>(w1, w2, wcT);
    k_ln_proj<<<768, 256, 0, stream>>>(M, ln_g, ln_b, b1, b2, wcT, aTf, bTf);
    k_opm<<<dim3(96, 64), 512, 0, stream>>>(aTf, bTf, wbTf, b_out, out);
}